// Round 1
// baseline (2159.890 us; speedup 1.0000x reference)
//
#include <hip/hip_runtime.h>
#include <math.h>

#define T_STEPS 100
#define BATCH   32
#define EMB     256
#define HID     512
#define FEATC   1024
#define VOCAB   32000
#define GATES   2048   // 4*HID
#define M_ROWS  (T_STEPS * BATCH)   // 3200
#define NWG     64     // persistent LSTM workgroups (8 units each)

typedef __attribute__((ext_vector_type(8))) short bf16x8;
typedef __attribute__((ext_vector_type(4))) float f32x4;

__device__ __forceinline__ unsigned short f2bf(float x) {
  union { float f; unsigned u; } v; v.f = x;
  unsigned r = v.u + 0x7fff + ((v.u >> 16) & 1);
  return (unsigned short)(r >> 16);
}
__device__ __forceinline__ float bf2f(unsigned short h) {
  union { float f; unsigned u; } v; v.u = ((unsigned)h) << 16;
  return v.f;
}

// ---------------------------------------------------------------------------
// Kernel A: adaptive-avg-pool(7x7) + fc -> h0, written as split bf16 into
// Hall slot 0 (slot s holds h AFTER step s-1; slot 0 = h0).
// ---------------------------------------------------------------------------
__global__ __launch_bounds__(512) void pool_fc_kernel(
    const float* __restrict__ features, const float* __restrict__ fc_w,
    const float* __restrict__ fc_b, unsigned short* __restrict__ h0_hi,
    unsigned short* __restrict__ h0_lo) {
  __shared__ float pooled_s[FEATC];
  const int b = blockIdx.x;
  const int tid = threadIdx.x;
  const float* fb = features + (size_t)b * FEATC * 49;
  for (int f = tid; f < FEATC; f += 512) {
    const float* p = fb + f * 49;
    float s = 0.f;
#pragma unroll
    for (int i = 0; i < 49; ++i) s += p[i];
    pooled_s[f] = s / 49.0f;
  }
  __syncthreads();
  const float4* w4 = (const float4*)(fc_w + (size_t)tid * FEATC);
  const float4* p4 = (const float4*)pooled_s;
  float acc = fc_b[tid];
#pragma unroll 8
  for (int k = 0; k < FEATC / 4; ++k) {
    float4 w = w4[k], p = p4[k];
    acc += w.x * p.x + w.y * p.y + w.z * p.z + w.w * p.w;
  }
  unsigned short hh = f2bf(acc);
  unsigned short hl = f2bf(acc - bf2f(hh));
  h0_hi[b * HID + tid] = hh;
  h0_lo[b * HID + tid] = hl;
}

// ---------------------------------------------------------------------------
// Kernel B: xg[m][col] = emb[tok[m]] @ W_ih.T + b_ih + b_hh  (fp32 tile GEMM)
// ---------------------------------------------------------------------------
#define BM 128
#define BN 128
#define BK 16
#define LDP (BM + 4)

__global__ __launch_bounds__(256) void xg_gemm_kernel(
    const int* __restrict__ reports, const float* __restrict__ emb,
    const float* __restrict__ W_ih, const float* __restrict__ b_ih,
    const float* __restrict__ b_hh, float* __restrict__ xg) {
  __shared__ float As[BK][LDP];
  __shared__ float Bs[BK][LDP];
  __shared__ int rowbase_s[BM];
  const int tid = threadIdx.x;
  const int n0 = blockIdx.x * BN;
  const int m0 = blockIdx.y * BM;
  if (tid < BM) {
    int m = m0 + tid;
    int t = m >> 5, b = m & 31;
    int tok = (t == 0) ? 1 : reports[b * T_STEPS + (t - 1)];
    rowbase_s[tid] = tok * EMB;
  }
  __syncthreads();

  float acc[8][8];
#pragma unroll
  for (int i = 0; i < 8; ++i)
#pragma unroll
    for (int j = 0; j < 8; ++j) acc[i][j] = 0.f;

  const int tx = tid & 15, ty = tid >> 4;

  for (int kt = 0; kt < EMB / BK; ++kt) {
    const int k0 = kt * BK;
#pragma unroll
    for (int l = 0; l < 2; ++l) {
      int idx = l * 256 + tid;
      int rm = idx >> 2;
      int kk = (idx & 3) * 4;
      float4 av = *(const float4*)(emb + rowbase_s[rm] + k0 + kk);
      As[kk + 0][rm] = av.x; As[kk + 1][rm] = av.y;
      As[kk + 2][rm] = av.z; As[kk + 3][rm] = av.w;
      float4 bvv = *(const float4*)(W_ih + (size_t)(n0 + rm) * EMB + k0 + kk);
      Bs[kk + 0][rm] = bvv.x; Bs[kk + 1][rm] = bvv.y;
      Bs[kk + 2][rm] = bvv.z; Bs[kk + 3][rm] = bvv.w;
    }
    __syncthreads();
#pragma unroll
    for (int kk = 0; kk < BK; ++kk) {
      float a[8], bf[8];
      *(float4*)(a)     = *(const float4*)&As[kk][ty * 4];
      *(float4*)(a + 4) = *(const float4*)&As[kk][64 + ty * 4];
      *(float4*)(bf)     = *(const float4*)&Bs[kk][tx * 4];
      *(float4*)(bf + 4) = *(const float4*)&Bs[kk][64 + tx * 4];
#pragma unroll
      for (int i = 0; i < 8; ++i)
#pragma unroll
        for (int j = 0; j < 8; ++j) acc[i][j] += a[i] * bf[j];
    }
    __syncthreads();
  }

#pragma unroll
  for (int i = 0; i < 8; ++i) {
    int m = m0 + ((i < 4) ? (ty * 4 + i) : (64 + ty * 4 + i - 4));
    float* orow = xg + (size_t)m * GATES;
    int c0 = n0 + tx * 4;
    int c1 = n0 + 64 + tx * 4;
    float4 r0, r1;
    r0.x = acc[i][0] + b_ih[c0 + 0] + b_hh[c0 + 0];
    r0.y = acc[i][1] + b_ih[c0 + 1] + b_hh[c0 + 1];
    r0.z = acc[i][2] + b_ih[c0 + 2] + b_hh[c0 + 2];
    r0.w = acc[i][3] + b_ih[c0 + 3] + b_hh[c0 + 3];
    r1.x = acc[i][4] + b_ih[c1 + 0] + b_hh[c1 + 0];
    r1.y = acc[i][5] + b_ih[c1 + 1] + b_hh[c1 + 1];
    r1.z = acc[i][6] + b_ih[c1 + 2] + b_hh[c1 + 2];
    r1.w = acc[i][7] + b_ih[c1 + 3] + b_hh[c1 + 3];
    *(float4*)(orow + c0) = r0;
    *(float4*)(orow + c1) = r1;
  }
}

// ---------------------------------------------------------------------------
// Kernel S: split fp32 -> bf16 hi/lo (for Wv)
// ---------------------------------------------------------------------------
__global__ __launch_bounds__(256) void split_kernel(
    const float* __restrict__ x, unsigned short* __restrict__ hi,
    unsigned short* __restrict__ lo, int n4) {
  int i = blockIdx.x * 256 + threadIdx.x;
  if (i >= n4) return;
  float4 v = ((const float4*)x)[i];
  ushort4 h, l;
  h.x = f2bf(v.x); l.x = f2bf(v.x - bf2f(h.x));
  h.y = f2bf(v.y); l.y = f2bf(v.y - bf2f(h.y));
  h.z = f2bf(v.z); l.z = f2bf(v.z - bf2f(h.z));
  h.w = f2bf(v.w); l.w = f2bf(v.w - bf2f(h.w));
  ((ushort4*)hi)[i] = h;
  ((ushort4*)lo)[i] = l;
}

// ---------------------------------------------------------------------------
// Kernel P: persistent LSTM — all 100 steps in ONE cooperative launch.
//   64 wgs x 256 threads; wg owns units [8*wg, 8*wg+8) => 32 gate rows.
//   W_hh slice lives in VGPRs as split-bf16 MFMA B-fragments (loaded once).
//   Per step: gates_hh = H(32x512) @ Wslice.T via 16x16x32 bf16 MFMA,
//   3-pass split-bf16 (same scheme as out_mfma). Each of 4 waves covers a
//   K=128 slice of the full 32x32 output; partials reduced through LDS.
//   h exchanged between wgs via Hall_hi/lo (slot t+1 = output of step t),
//   which the logits GEMM consumes anyway. Flag barrier per step
//   (release fence -> per-wg flag -> lane-parallel poll -> acquire fence).
//   c state persists in a register of the owning (b,u) thread.
// ---------------------------------------------------------------------------
__global__ __launch_bounds__(256) void lstm_persist_kernel(
    const float* __restrict__ W_hh, const float* __restrict__ xg,
    unsigned short* __restrict__ Hall_hi, unsigned short* __restrict__ Hall_lo,
    unsigned* __restrict__ flags) {
  __shared__ float part[4][32][32];   // per-wave K-slice partials (16 KB)
  __shared__ float gsm[32][32];       // reduced gates [batch][g*8+u] (4 KB)
  const int tid = threadIdx.x;
  const int wg = blockIdx.x;
  const int w = tid >> 6;        // wave = K-slice 0..3 (128 k each)
  const int lane = tid & 63;
  const int rl = lane & 15;      // fragment row within 16
  const int q = lane >> 4;       // k-quad 0..3 (8 bf16 each)

  // ---- preload W_hh slice into registers as split-bf16 B-fragments ----
  // B-fragment (mirrors out_mfma): lane holds row n=(ni*16+rl), k=(kt*32+q*8..+8)
  bf16x8 wbh[4][2], wbl[4][2];
#pragma unroll
  for (int kt = 0; kt < 4; ++kt) {
#pragma unroll
    for (int ni = 0; ni < 2; ++ni) {
      const int n = ni * 16 + rl;
      const int grow = (n >> 3) * HID + wg * 8 + (n & 7);   // torch gate order i,f,g,o
      const float* src = W_hh + (size_t)grow * HID + w * 128 + kt * 32 + q * 8;
      float4 v0 = *(const float4*)(src);
      float4 v1 = *(const float4*)(src + 4);
      float vv[8] = {v0.x, v0.y, v0.z, v0.w, v1.x, v1.y, v1.z, v1.w};
      bf16x8 hb, lb;
#pragma unroll
      for (int j = 0; j < 8; ++j) {
        unsigned short h = f2bf(vv[j]);
        hb[j] = (short)h;
        lb[j] = (short)f2bf(vv[j] - bf2f(h));
      }
      wbh[kt][ni] = hb;
      wbl[kt][ni] = lb;
    }
  }

  // activation-thread ownership: (batch ab, unit au) — same thread each step
  const int ab = tid >> 3;       // 0..31
  const int au = tid & 7;        // 0..7
  float c_reg = 0.f;

  for (int t = 0; t < T_STEPS; ++t) {
    if (t > 0) {
      if (tid < NWG) {
        while (__hip_atomic_load(&flags[tid], __ATOMIC_RELAXED,
                                 __HIP_MEMORY_SCOPE_AGENT) < (unsigned)t) {
          __builtin_amdgcn_s_sleep(1);
        }
      }
      __syncthreads();
      __threadfence();   // acquire: invalidate before reading remote h
    }

    // ---- A fragments straight from global (Hall slot t = h input) ----
    const unsigned short* Ah = Hall_hi + (size_t)t * (BATCH * HID);
    const unsigned short* Al = Hall_lo + (size_t)t * (BATCH * HID);
    f32x4 acc[2][2] = {};
#pragma unroll
    for (int kt = 0; kt < 4; ++kt) {
      const int k0 = w * 128 + kt * 32 + q * 8;
      bf16x8 ah[2], al[2];
#pragma unroll
      for (int mi = 0; mi < 2; ++mi) {
        const size_t off = (size_t)(mi * 16 + rl) * HID + k0;
        ah[mi] = *(const bf16x8*)(Ah + off);
        al[mi] = *(const bf16x8*)(Al + off);
      }
#pragma unroll
      for (int mi = 0; mi < 2; ++mi)
#pragma unroll
        for (int ni = 0; ni < 2; ++ni) {
          acc[mi][ni] = __builtin_amdgcn_mfma_f32_16x16x32_bf16(ah[mi], wbh[kt][ni], acc[mi][ni], 0, 0, 0);
          acc[mi][ni] = __builtin_amdgcn_mfma_f32_16x16x32_bf16(al[mi], wbh[kt][ni], acc[mi][ni], 0, 0, 0);
          acc[mi][ni] = __builtin_amdgcn_mfma_f32_16x16x32_bf16(ah[mi], wbl[kt][ni], acc[mi][ni], 0, 0, 0);
        }
    }

    // ---- dump K-slice partials: C/D layout col=lane&15, row=q*4+r ----
#pragma unroll
    for (int mi = 0; mi < 2; ++mi)
#pragma unroll
      for (int ni = 0; ni < 2; ++ni)
#pragma unroll
        for (int r = 0; r < 4; ++r)
          part[w][mi * 16 + q * 4 + r][ni * 16 + rl] = acc[mi][ni][r];
    __syncthreads();

    // ---- reduce 4 K-slices + xg -> gates ----
    {
      const int m = tid >> 3;
      const int n4 = (tid & 7) * 4;
      float4 s0 = *(float4*)&part[0][m][n4];
      float4 s1 = *(float4*)&part[1][m][n4];
      float4 s2 = *(float4*)&part[2][m][n4];
      float4 s3 = *(float4*)&part[3][m][n4];
      const float4 xv = *(const float4*)(
          xg + ((size_t)t * BATCH + m) * GATES + (n4 >> 3) * HID + wg * 8 + (n4 & 7));
      float4 g;
      g.x = s0.x + s1.x + s2.x + s3.x + xv.x;
      g.y = s0.y + s1.y + s2.y + s3.y + xv.y;
      g.z = s0.z + s1.z + s2.z + s3.z + xv.z;
      g.w = s0.w + s1.w + s2.w + s3.w + xv.w;
      *(float4*)&gsm[m][n4] = g;
    }
    __syncthreads();

    // ---- activation + state update + publish h (split bf16, slot t+1) ----
    {
      float iv = gsm[ab][au];
      float fv = gsm[ab][8 + au];
      float gv = gsm[ab][16 + au];
      float ov = gsm[ab][24 + au];
      float si = 1.f / (1.f + expf(-iv));
      float sf = 1.f / (1.f + expf(-fv));
      float sg = tanhf(gv);
      float so = 1.f / (1.f + expf(-ov));
      c_reg = sf * c_reg + si * sg;
      float hn = so * tanhf(c_reg);
      unsigned short hh = f2bf(hn);
      unsigned short hl = f2bf(hn - bf2f(hh));
      const size_t hidx = (size_t)(t + 1) * (BATCH * HID) + (size_t)ab * HID + wg * 8 + au;
      Hall_hi[hidx] = hh;
      Hall_lo[hidx] = hl;
    }
    __syncthreads();   // all stores issued (vmcnt drained per-wave at barrier)

    if (tid == 0) {
      __threadfence();   // release: write back L2 so other XCDs see Hall[t+1]
      __hip_atomic_store(&flags[wg], (unsigned)(t + 1), __ATOMIC_RELEASE,
                         __HIP_MEMORY_SCOPE_AGENT);
    }
  }
}

// ---------------------------------------------------------------------------
// Kernel D: logits = Hall @ Wv.T + bv via split-bf16 MFMA (3 passes, fp32 acc)
// ---------------------------------------------------------------------------
__global__ __launch_bounds__(256, 2) void out_mfma_kernel(
    const unsigned short* __restrict__ Ahi, const unsigned short* __restrict__ Alo,
    const unsigned short* __restrict__ Bhi, const unsigned short* __restrict__ Blo,
    const float* __restrict__ bv, float* __restrict__ out) {
  __shared__ unsigned short Ah[128 * 32], Al[128 * 32], Bh[128 * 32], Bl[128 * 32];
  const int tid = threadIdx.x;
  const int lane = tid & 63;
  const int w = tid >> 6;
  const int wm = w & 1, wn = w >> 1;
  const int m0 = blockIdx.x * 128;
  const int n0 = blockIdx.y * 128;

  f32x4 acc[4][4] = {};

  const int srow4 = lane >> 2;                          // staging row-within-16
  const int skoff = ((lane & 3) ^ ((lane >> 3) & 3)) * 8;  // swizzled k-chunk

  for (int kt = 0; kt < 16; ++kt) {
    const int k0 = kt * 32;
#pragma unroll
    for (int issue = 0; issue < 2; ++issue) {
      const int r = w * 32 + issue * 16 + srow4;
      const size_t gA = (size_t)(m0 + r) * 512 + k0 + skoff;
      const size_t gB = (size_t)(n0 + r) * 512 + k0 + skoff;
      const int loff = (w * 32 + issue * 16) * 32;
      __builtin_amdgcn_global_load_lds(
          (const __attribute__((address_space(1))) void*)(Ahi + gA),
          (__attribute__((address_space(3))) void*)(Ah + loff), 16, 0, 0);
      __builtin_amdgcn_global_load_lds(
          (const __attribute__((address_space(1))) void*)(Alo + gA),
          (__attribute__((address_space(3))) void*)(Al + loff), 16, 0, 0);
      __builtin_amdgcn_global_load_lds(
          (const __attribute__((address_space(1))) void*)(Bhi + gB),
          (__attribute__((address_space(3))) void*)(Bh + loff), 16, 0, 0);
      __builtin_amdgcn_global_load_lds(
          (const __attribute__((address_space(1))) void*)(Blo + gB),
          (__attribute__((address_space(3))) void*)(Bl + loff), 16, 0, 0);
    }
    __syncthreads();

    bf16x8 ah[4], al[4], bh[4], bl[4];
    const int q = lane >> 4;                 // k-quad 0..3
    const int rl = lane & 15;
    const int slot = (q ^ ((rl >> 1) & 3)) * 8;
#pragma unroll
    for (int i = 0; i < 4; ++i) {
      int arow = wm * 64 + i * 16 + rl;
      ah[i] = *(const bf16x8*)&Ah[arow * 32 + slot];
      al[i] = *(const bf16x8*)&Al[arow * 32 + slot];
      int brow = wn * 64 + i * 16 + rl;
      bh[i] = *(const bf16x8*)&Bh[brow * 32 + slot];
      bl[i] = *(const bf16x8*)&Bl[brow * 32 + slot];
    }
#pragma unroll
    for (int i = 0; i < 4; ++i)
#pragma unroll
      for (int jj = 0; jj < 4; ++jj) {
        acc[i][jj] = __builtin_amdgcn_mfma_f32_16x16x32_bf16(ah[i], bh[jj], acc[i][jj], 0, 0, 0);
        acc[i][jj] = __builtin_amdgcn_mfma_f32_16x16x32_bf16(al[i], bh[jj], acc[i][jj], 0, 0, 0);
        acc[i][jj] = __builtin_amdgcn_mfma_f32_16x16x32_bf16(ah[i], bl[jj], acc[i][jj], 0, 0, 0);
      }
    __syncthreads();
  }

  // epilogue: D[m = (lane>>4)*4 + reg][n = lane&15]; out is (B,T,V), m = t*32+b
#pragma unroll
  for (int jj = 0; jj < 4; ++jj) {
    const int ncol = n0 + wn * 64 + jj * 16 + (lane & 15);
    const float bvn = bv[ncol];
#pragma unroll
    for (int i = 0; i < 4; ++i) {
      const int mbase = m0 + wm * 64 + i * 16 + (lane >> 4) * 4;
#pragma unroll
      for (int r = 0; r < 4; ++r) {
        const int m = mbase + r;
        const int t = m >> 5, b = m & 31;
        out[((size_t)(b * T_STEPS + t)) * VOCAB + ncol] = acc[i][jj][r] + bvn;
      }
    }
  }
}

// ---------------------------------------------------------------------------
extern "C" void kernel_launch(void* const* d_in, const int* in_sizes, int n_in,
                              void* d_out, int out_size, void* d_ws, size_t ws_size,
                              hipStream_t stream) {
  const float* features = (const float*)d_in[0];
  const int*   reports  = (const int*)d_in[1];
  const float* emb      = (const float*)d_in[2];
  const float* fc_w     = (const float*)d_in[3];
  const float* fc_b     = (const float*)d_in[4];
  const float* W_ih     = (const float*)d_in[5];
  const float* b_ih     = (const float*)d_in[6];
  const float* W_hh     = (const float*)d_in[7];
  const float* b_hh     = (const float*)d_in[8];
  const float* Wv       = (const float*)d_in[9];
  const float* bv       = (const float*)d_in[10];
  float* out = (float*)d_out;

  // workspace layout (total ~93.8 MiB, <= previous session's 94 MiB usage):
  //   xg:      3200*2048 f32                       (26.2 MB)
  //   Hall_hi: (T+1)*32*512 bf16 (slot 0 = h0)     ( 3.3 MB)
  //   Hall_lo: (T+1)*32*512 bf16                   ( 3.3 MB)
  //   Wv_hi/lo: 32000*512 bf16 each                (65.5 MB)
  //   flags:   NWG u32 barrier flags
  float* ws = (float*)d_ws;
  float* xg = ws;
  unsigned short* Hall_hi = (unsigned short*)(xg + (size_t)M_ROWS * GATES);
  unsigned short* Hall_lo = Hall_hi + (size_t)(T_STEPS + 1) * BATCH * HID;
  unsigned short* Wv_hi   = Hall_lo + (size_t)(T_STEPS + 1) * BATCH * HID;
  unsigned short* Wv_lo   = Wv_hi + (size_t)VOCAB * HID;
  unsigned*       flags   = (unsigned*)(Wv_lo + (size_t)VOCAB * HID);

  hipMemsetAsync(flags, 0, NWG * sizeof(unsigned), stream);

  pool_fc_kernel<<<BATCH, 512, 0, stream>>>(features, fc_w, fc_b, Hall_hi, Hall_lo);
  xg_gemm_kernel<<<dim3(GATES / BN, M_ROWS / BM), 256, 0, stream>>>(
      reports, emb, W_ih, b_ih, b_hh, xg);
  {
    int n4 = VOCAB * HID / 4;
    split_kernel<<<(n4 + 255) / 256, 256, 0, stream>>>(Wv, Wv_hi, Wv_lo, n4);
  }
  {
    void* kargs[] = {(void*)&W_hh, (void*)&xg, (void*)&Hall_hi, (void*)&Hall_lo,
                     (void*)&flags};
    hipLaunchCooperativeKernel((const void*)lstm_persist_kernel, dim3(NWG),
                               dim3(256), kargs, 0, stream);
  }
  out_mfma_kernel<<<dim3(M_ROWS / 128, VOCAB / 128), 256, 0, stream>>>(
      Hall_hi + (size_t)BATCH * HID, Hall_lo + (size_t)BATCH * HID,
      Wv_hi, Wv_lo, bv, out);
}

// Round 2
// 2069.365 us; speedup vs baseline: 1.0437x; 1.0437x over previous
//
#include <hip/hip_runtime.h>
#include <math.h>

#define T_STEPS 100
#define BATCH   32
#define EMB     256
#define HID     512
#define FEATC   1024
#define VOCAB   32000
#define GATES   2048   // 4*HID
#define M_ROWS  (T_STEPS * BATCH)   // 3200
#define NWG     64     // persistent LSTM workgroups (8 units each)

typedef __attribute__((ext_vector_type(8))) short bf16x8;
typedef __attribute__((ext_vector_type(4))) float f32x4;

__device__ __forceinline__ unsigned short f2bf(float x) {
  union { float f; unsigned u; } v; v.f = x;
  unsigned r = v.u + 0x7fff + ((v.u >> 16) & 1);
  return (unsigned short)(r >> 16);
}
__device__ __forceinline__ float bf2f(unsigned short h) {
  union { float f; unsigned u; } v; v.u = ((unsigned)h) << 16;
  return v.f;
}

// coherent (agent-scope, L2-bypassing) 16B fragment load: 4 relaxed sc1 dwords,
// bit-identical to bf16x8 (u32 d covers bf16 elements 2d, 2d+1 little-endian).
__device__ __forceinline__ bf16x8 load_frag_coh(const unsigned* p) {
  union { unsigned u[4]; bf16x8 v; } r;
#pragma unroll
  for (int j = 0; j < 4; ++j)
    r.u[j] = __hip_atomic_load(p + j, __ATOMIC_RELAXED, __HIP_MEMORY_SCOPE_AGENT);
  return r.v;
}

// ---------------------------------------------------------------------------
// Kernel A: adaptive-avg-pool(7x7) + fc -> h0, written as split bf16 into
// Hall slot 0 (slot s holds h AFTER step s-1; slot 0 = h0).
// ---------------------------------------------------------------------------
__global__ __launch_bounds__(512) void pool_fc_kernel(
    const float* __restrict__ features, const float* __restrict__ fc_w,
    const float* __restrict__ fc_b, unsigned short* __restrict__ h0_hi,
    unsigned short* __restrict__ h0_lo) {
  __shared__ float pooled_s[FEATC];
  const int b = blockIdx.x;
  const int tid = threadIdx.x;
  const float* fb = features + (size_t)b * FEATC * 49;
  for (int f = tid; f < FEATC; f += 512) {
    const float* p = fb + f * 49;
    float s = 0.f;
#pragma unroll
    for (int i = 0; i < 49; ++i) s += p[i];
    pooled_s[f] = s / 49.0f;
  }
  __syncthreads();
  const float4* w4 = (const float4*)(fc_w + (size_t)tid * FEATC);
  const float4* p4 = (const float4*)pooled_s;
  float acc = fc_b[tid];
#pragma unroll 8
  for (int k = 0; k < FEATC / 4; ++k) {
    float4 w = w4[k], p = p4[k];
    acc += w.x * p.x + w.y * p.y + w.z * p.z + w.w * p.w;
  }
  unsigned short hh = f2bf(acc);
  unsigned short hl = f2bf(acc - bf2f(hh));
  h0_hi[b * HID + tid] = hh;
  h0_lo[b * HID + tid] = hl;
}

// ---------------------------------------------------------------------------
// Kernel B: xg[m][col] = emb[tok[m]] @ W_ih.T + b_ih + b_hh  (fp32 tile GEMM)
// ---------------------------------------------------------------------------
#define BM 128
#define BN 128
#define BK 16
#define LDP (BM + 4)

__global__ __launch_bounds__(256) void xg_gemm_kernel(
    const int* __restrict__ reports, const float* __restrict__ emb,
    const float* __restrict__ W_ih, const float* __restrict__ b_ih,
    const float* __restrict__ b_hh, float* __restrict__ xg) {
  __shared__ float As[BK][LDP];
  __shared__ float Bs[BK][LDP];
  __shared__ int rowbase_s[BM];
  const int tid = threadIdx.x;
  const int n0 = blockIdx.x * BN;
  const int m0 = blockIdx.y * BM;
  if (tid < BM) {
    int m = m0 + tid;
    int t = m >> 5, b = m & 31;
    int tok = (t == 0) ? 1 : reports[b * T_STEPS + (t - 1)];
    rowbase_s[tid] = tok * EMB;
  }
  __syncthreads();

  float acc[8][8];
#pragma unroll
  for (int i = 0; i < 8; ++i)
#pragma unroll
    for (int j = 0; j < 8; ++j) acc[i][j] = 0.f;

  const int tx = tid & 15, ty = tid >> 4;

  for (int kt = 0; kt < EMB / BK; ++kt) {
    const int k0 = kt * BK;
#pragma unroll
    for (int l = 0; l < 2; ++l) {
      int idx = l * 256 + tid;
      int rm = idx >> 2;
      int kk = (idx & 3) * 4;
      float4 av = *(const float4*)(emb + rowbase_s[rm] + k0 + kk);
      As[kk + 0][rm] = av.x; As[kk + 1][rm] = av.y;
      As[kk + 2][rm] = av.z; As[kk + 3][rm] = av.w;
      float4 bvv = *(const float4*)(W_ih + (size_t)(n0 + rm) * EMB + k0 + kk);
      Bs[kk + 0][rm] = bvv.x; Bs[kk + 1][rm] = bvv.y;
      Bs[kk + 2][rm] = bvv.z; Bs[kk + 3][rm] = bvv.w;
    }
    __syncthreads();
#pragma unroll
    for (int kk = 0; kk < BK; ++kk) {
      float a[8], bf[8];
      *(float4*)(a)     = *(const float4*)&As[kk][ty * 4];
      *(float4*)(a + 4) = *(const float4*)&As[kk][64 + ty * 4];
      *(float4*)(bf)     = *(const float4*)&Bs[kk][tx * 4];
      *(float4*)(bf + 4) = *(const float4*)&Bs[kk][64 + tx * 4];
#pragma unroll
      for (int i = 0; i < 8; ++i)
#pragma unroll
        for (int j = 0; j < 8; ++j) acc[i][j] += a[i] * bf[j];
    }
    __syncthreads();
  }

#pragma unroll
  for (int i = 0; i < 8; ++i) {
    int m = m0 + ((i < 4) ? (ty * 4 + i) : (64 + ty * 4 + i - 4));
    float* orow = xg + (size_t)m * GATES;
    int c0 = n0 + tx * 4;
    int c1 = n0 + 64 + tx * 4;
    float4 r0, r1;
    r0.x = acc[i][0] + b_ih[c0 + 0] + b_hh[c0 + 0];
    r0.y = acc[i][1] + b_ih[c0 + 1] + b_hh[c0 + 1];
    r0.z = acc[i][2] + b_ih[c0 + 2] + b_hh[c0 + 2];
    r0.w = acc[i][3] + b_ih[c0 + 3] + b_hh[c0 + 3];
    r1.x = acc[i][4] + b_ih[c1 + 0] + b_hh[c1 + 0];
    r1.y = acc[i][5] + b_ih[c1 + 1] + b_hh[c1 + 1];
    r1.z = acc[i][6] + b_ih[c1 + 2] + b_hh[c1 + 2];
    r1.w = acc[i][7] + b_ih[c1 + 3] + b_hh[c1 + 3];
    *(float4*)(orow + c0) = r0;
    *(float4*)(orow + c1) = r1;
  }
}

// ---------------------------------------------------------------------------
// Kernel S: split fp32 -> bf16 hi/lo (for Wv)
// ---------------------------------------------------------------------------
__global__ __launch_bounds__(256) void split_kernel(
    const float* __restrict__ x, unsigned short* __restrict__ hi,
    unsigned short* __restrict__ lo, int n4) {
  int i = blockIdx.x * 256 + threadIdx.x;
  if (i >= n4) return;
  float4 v = ((const float4*)x)[i];
  ushort4 h, l;
  h.x = f2bf(v.x); l.x = f2bf(v.x - bf2f(h.x));
  h.y = f2bf(v.y); l.y = f2bf(v.y - bf2f(h.y));
  h.z = f2bf(v.z); l.z = f2bf(v.z - bf2f(h.z));
  h.w = f2bf(v.w); l.w = f2bf(v.w - bf2f(h.w));
  ((ushort4*)hi)[i] = h;
  ((ushort4*)lo)[i] = l;
}

// ---------------------------------------------------------------------------
// Kernel P: persistent LSTM — all 100 steps, ONE cooperative launch.
//   FENCE-FREE cross-WG exchange: h is published/read with relaxed AGENT-scope
//   atomics (sc1: bypass per-XCD L2, coherent at LLC). NO __threadfence — the
//   round-1 version spent ~10us/step in buffer_inv/buffer_wbl2 (whole-L2
//   cache maintenance), matching the per-launch dispatch fences it replaced.
//   Ordering: __syncthreads drains vmcnt per wave, so all sc1 h-stores are
//   LLC-visible before tid0's relaxed flag store; consumers poll relaxed sc1.
//   Publish threads own a UNIT PAIR so stores are 4B-atomic u32 into the
//   planar hi/lo arrays (no extra buffer, bit-compatible with out_mfma).
// ---------------------------------------------------------------------------
__global__ __launch_bounds__(256) void lstm_persist_kernel(
    const float* __restrict__ W_hh, const float* __restrict__ xg,
    unsigned short* __restrict__ Hall_hi, unsigned short* __restrict__ Hall_lo,
    unsigned* __restrict__ flags) {
  __shared__ float part[4][32][32];   // per-wave K-slice partials (16 KB)
  __shared__ float gsm[32][32];       // reduced gates [batch][g*8+u] (4 KB)
  const int tid = threadIdx.x;
  const int wg = blockIdx.x;
  const int w = tid >> 6;        // wave = K-slice 0..3 (128 k each)
  const int lane = tid & 63;
  const int rl = lane & 15;      // fragment row within 16
  const int q = lane >> 4;       // k-quad 0..3 (8 bf16 each)

  // ---- preload W_hh slice into registers as split-bf16 B-fragments ----
  bf16x8 wbh[4][2], wbl[4][2];
#pragma unroll
  for (int kt = 0; kt < 4; ++kt) {
#pragma unroll
    for (int ni = 0; ni < 2; ++ni) {
      const int n = ni * 16 + rl;
      const int grow = (n >> 3) * HID + wg * 8 + (n & 7);   // torch gate order i,f,g,o
      const float* src = W_hh + (size_t)grow * HID + w * 128 + kt * 32 + q * 8;
      float4 v0 = *(const float4*)(src);
      float4 v1 = *(const float4*)(src + 4);
      float vv[8] = {v0.x, v0.y, v0.z, v0.w, v1.x, v1.y, v1.z, v1.w};
      bf16x8 hb, lb;
#pragma unroll
      for (int j = 0; j < 8; ++j) {
        unsigned short h = f2bf(vv[j]);
        hb[j] = (short)h;
        lb[j] = (short)f2bf(vv[j] - bf2f(h));
      }
      wbh[kt][ni] = hb;
      wbl[kt][ni] = lb;
    }
  }

  // activation ownership: thread (tid<128) owns (batch ab, unit pair aup)
  const int ab = tid >> 2;       // 0..31  (for tid<128)
  const int aup = tid & 3;       // unit pair -> units 2*aup, 2*aup+1
  float c0r = 0.f, c1r = 0.f;

  for (int t = 0; t < T_STEPS; ++t) {
    if (t > 0) {
      if (tid < NWG) {
        while (__hip_atomic_load(&flags[tid], __ATOMIC_RELAXED,
                                 __HIP_MEMORY_SCOPE_AGENT) < (unsigned)t) {
          __builtin_amdgcn_s_sleep(1);
        }
      }
      __syncthreads();
    }

    // ---- A fragments: coherent sc1 loads from Hall slot t ----
    const unsigned* Ahp = (const unsigned*)(Hall_hi + (size_t)t * (BATCH * HID));
    const unsigned* Alp = (const unsigned*)(Hall_lo + (size_t)t * (BATCH * HID));
    f32x4 acc[2][2] = {};
#pragma unroll
    for (int kt = 0; kt < 4; ++kt) {
      const int k0 = w * 128 + kt * 32 + q * 8;
      bf16x8 ah[2], al[2];
#pragma unroll
      for (int mi = 0; mi < 2; ++mi) {
        const size_t doff = ((size_t)(mi * 16 + rl) * HID + k0) >> 1;  // u32 idx
        ah[mi] = load_frag_coh(Ahp + doff);
        al[mi] = load_frag_coh(Alp + doff);
      }
#pragma unroll
      for (int mi = 0; mi < 2; ++mi)
#pragma unroll
        for (int ni = 0; ni < 2; ++ni) {
          acc[mi][ni] = __builtin_amdgcn_mfma_f32_16x16x32_bf16(ah[mi], wbh[kt][ni], acc[mi][ni], 0, 0, 0);
          acc[mi][ni] = __builtin_amdgcn_mfma_f32_16x16x32_bf16(al[mi], wbh[kt][ni], acc[mi][ni], 0, 0, 0);
          acc[mi][ni] = __builtin_amdgcn_mfma_f32_16x16x32_bf16(ah[mi], wbl[kt][ni], acc[mi][ni], 0, 0, 0);
        }
    }

    // ---- dump K-slice partials: C/D layout col=lane&15, row=q*4+r ----
#pragma unroll
    for (int mi = 0; mi < 2; ++mi)
#pragma unroll
      for (int ni = 0; ni < 2; ++ni)
#pragma unroll
        for (int r = 0; r < 4; ++r)
          part[w][mi * 16 + q * 4 + r][ni * 16 + rl] = acc[mi][ni][r];
    __syncthreads();

    // ---- reduce 4 K-slices + xg -> gates ----
    {
      const int m = tid >> 3;
      const int n4 = (tid & 7) * 4;
      float4 s0 = *(float4*)&part[0][m][n4];
      float4 s1 = *(float4*)&part[1][m][n4];
      float4 s2 = *(float4*)&part[2][m][n4];
      float4 s3 = *(float4*)&part[3][m][n4];
      const float4 xv = *(const float4*)(
          xg + ((size_t)t * BATCH + m) * GATES + (n4 >> 3) * HID + wg * 8 + (n4 & 7));
      float4 g;
      g.x = s0.x + s1.x + s2.x + s3.x + xv.x;
      g.y = s0.y + s1.y + s2.y + s3.y + xv.y;
      g.z = s0.z + s1.z + s2.z + s3.z + xv.z;
      g.w = s0.w + s1.w + s2.w + s3.w + xv.w;
      *(float4*)&gsm[m][n4] = g;
    }
    __syncthreads();

    // ---- activation + state + publish h (unit pair per thread, sc1 u32) ----
    if (tid < 128) {
      const int u0 = 2 * aup, u1 = u0 + 1;
      float iv0 = gsm[ab][u0],      iv1 = gsm[ab][u1];
      float fv0 = gsm[ab][8 + u0],  fv1 = gsm[ab][8 + u1];
      float gv0 = gsm[ab][16 + u0], gv1 = gsm[ab][16 + u1];
      float ov0 = gsm[ab][24 + u0], ov1 = gsm[ab][24 + u1];
      float si0 = 1.f / (1.f + expf(-iv0)), si1 = 1.f / (1.f + expf(-iv1));
      float sf0 = 1.f / (1.f + expf(-fv0)), sf1 = 1.f / (1.f + expf(-fv1));
      float sg0 = tanhf(gv0),               sg1 = tanhf(gv1);
      float so0 = 1.f / (1.f + expf(-ov0)), so1 = 1.f / (1.f + expf(-ov1));
      c0r = sf0 * c0r + si0 * sg0;
      c1r = sf1 * c1r + si1 * sg1;
      float h0 = so0 * tanhf(c0r);
      float h1 = so1 * tanhf(c1r);
      unsigned short hh0 = f2bf(h0), hl0 = f2bf(h0 - bf2f(hh0));
      unsigned short hh1 = f2bf(h1), hl1 = f2bf(h1 - bf2f(hh1));
      unsigned packh = (unsigned)hh0 | ((unsigned)hh1 << 16);
      unsigned packl = (unsigned)hl0 | ((unsigned)hl1 << 16);
      const size_t du = ((size_t)(t + 1) * (BATCH * HID) +
                         (size_t)ab * HID + wg * 8 + u0) >> 1;  // u32 idx
      __hip_atomic_store((unsigned*)Hall_hi + du, packh, __ATOMIC_RELAXED,
                         __HIP_MEMORY_SCOPE_AGENT);
      __hip_atomic_store((unsigned*)Hall_lo + du, packl, __ATOMIC_RELAXED,
                         __HIP_MEMORY_SCOPE_AGENT);
    }
    __syncthreads();   // drains vmcnt per wave -> h stores LLC-visible

    if (tid == 0) {
      __hip_atomic_store(&flags[wg], (unsigned)(t + 1), __ATOMIC_RELAXED,
                         __HIP_MEMORY_SCOPE_AGENT);
    }
  }
}

// ---------------------------------------------------------------------------
// Kernel D: logits = Hall @ Wv.T + bv via split-bf16 MFMA (3 passes, fp32 acc)
//   Output stores are NON-TEMPORAL: the 410MB logits stream was evicting the
//   72MB working set (Wv+Hall) from LLC -> 1.4GB HBM re-fetch.
// ---------------------------------------------------------------------------
__global__ __launch_bounds__(256, 2) void out_mfma_kernel(
    const unsigned short* __restrict__ Ahi, const unsigned short* __restrict__ Alo,
    const unsigned short* __restrict__ Bhi, const unsigned short* __restrict__ Blo,
    const float* __restrict__ bv, float* __restrict__ out) {
  __shared__ unsigned short Ah[128 * 32], Al[128 * 32], Bh[128 * 32], Bl[128 * 32];
  const int tid = threadIdx.x;
  const int lane = tid & 63;
  const int w = tid >> 6;
  const int wm = w & 1, wn = w >> 1;
  const int m0 = blockIdx.x * 128;
  const int n0 = blockIdx.y * 128;

  f32x4 acc[4][4] = {};

  const int srow4 = lane >> 2;                          // staging row-within-16
  const int skoff = ((lane & 3) ^ ((lane >> 3) & 3)) * 8;  // swizzled k-chunk

  for (int kt = 0; kt < 16; ++kt) {
    const int k0 = kt * 32;
#pragma unroll
    for (int issue = 0; issue < 2; ++issue) {
      const int r = w * 32 + issue * 16 + srow4;
      const size_t gA = (size_t)(m0 + r) * 512 + k0 + skoff;
      const size_t gB = (size_t)(n0 + r) * 512 + k0 + skoff;
      const int loff = (w * 32 + issue * 16) * 32;
      __builtin_amdgcn_global_load_lds(
          (const __attribute__((address_space(1))) void*)(Ahi + gA),
          (__attribute__((address_space(3))) void*)(Ah + loff), 16, 0, 0);
      __builtin_amdgcn_global_load_lds(
          (const __attribute__((address_space(1))) void*)(Alo + gA),
          (__attribute__((address_space(3))) void*)(Al + loff), 16, 0, 0);
      __builtin_amdgcn_global_load_lds(
          (const __attribute__((address_space(1))) void*)(Bhi + gB),
          (__attribute__((address_space(3))) void*)(Bh + loff), 16, 0, 0);
      __builtin_amdgcn_global_load_lds(
          (const __attribute__((address_space(1))) void*)(Blo + gB),
          (__attribute__((address_space(3))) void*)(Bl + loff), 16, 0, 0);
    }
    __syncthreads();

    bf16x8 ah[4], al[4], bh[4], bl[4];
    const int q = lane >> 4;                 // k-quad 0..3
    const int rl = lane & 15;
    const int slot = (q ^ ((rl >> 1) & 3)) * 8;
#pragma unroll
    for (int i = 0; i < 4; ++i) {
      int arow = wm * 64 + i * 16 + rl;
      ah[i] = *(const bf16x8*)&Ah[arow * 32 + slot];
      al[i] = *(const bf16x8*)&Al[arow * 32 + slot];
      int brow = wn * 64 + i * 16 + rl;
      bh[i] = *(const bf16x8*)&Bh[brow * 32 + slot];
      bl[i] = *(const bf16x8*)&Bl[brow * 32 + slot];
    }
#pragma unroll
    for (int i = 0; i < 4; ++i)
#pragma unroll
      for (int jj = 0; jj < 4; ++jj) {
        acc[i][jj] = __builtin_amdgcn_mfma_f32_16x16x32_bf16(ah[i], bh[jj], acc[i][jj], 0, 0, 0);
        acc[i][jj] = __builtin_amdgcn_mfma_f32_16x16x32_bf16(al[i], bh[jj], acc[i][jj], 0, 0, 0);
        acc[i][jj] = __builtin_amdgcn_mfma_f32_16x16x32_bf16(ah[i], bl[jj], acc[i][jj], 0, 0, 0);
      }
    __syncthreads();
  }

  // epilogue: D[m = (lane>>4)*4 + reg][n = lane&15]; out is (B,T,V), m = t*32+b
#pragma unroll
  for (int jj = 0; jj < 4; ++jj) {
    const int ncol = n0 + wn * 64 + jj * 16 + (lane & 15);
    const float bvn = bv[ncol];
#pragma unroll
    for (int i = 0; i < 4; ++i) {
      const int mbase = m0 + wm * 64 + i * 16 + (lane >> 4) * 4;
#pragma unroll
      for (int r = 0; r < 4; ++r) {
        const int m = mbase + r;
        const int t = m >> 5, b = m & 31;
        __builtin_nontemporal_store(
            acc[i][jj][r] + bvn,
            &out[((size_t)(b * T_STEPS + t)) * VOCAB + ncol]);
      }
    }
  }
}

// ---------------------------------------------------------------------------
extern "C" void kernel_launch(void* const* d_in, const int* in_sizes, int n_in,
                              void* d_out, int out_size, void* d_ws, size_t ws_size,
                              hipStream_t stream) {
  const float* features = (const float*)d_in[0];
  const int*   reports  = (const int*)d_in[1];
  const float* emb      = (const float*)d_in[2];
  const float* fc_w     = (const float*)d_in[3];
  const float* fc_b     = (const float*)d_in[4];
  const float* W_ih     = (const float*)d_in[5];
  const float* b_ih     = (const float*)d_in[6];
  const float* W_hh     = (const float*)d_in[7];
  const float* b_hh     = (const float*)d_in[8];
  const float* Wv       = (const float*)d_in[9];
  const float* bv       = (const float*)d_in[10];
  float* out = (float*)d_out;

  // workspace layout (~98.4 MiB):
  //   xg:      3200*2048 f32                       (26.2 MB)
  //   Hall_hi: (T+1)*32*512 bf16 (slot 0 = h0)     ( 3.3 MB)
  //   Hall_lo: (T+1)*32*512 bf16                   ( 3.3 MB)
  //   Wv_hi/lo: 32000*512 bf16 each                (65.5 MB)
  //   flags:   NWG u32 barrier flags
  float* ws = (float*)d_ws;
  float* xg = ws;
  unsigned short* Hall_hi = (unsigned short*)(xg + (size_t)M_ROWS * GATES);
  unsigned short* Hall_lo = Hall_hi + (size_t)(T_STEPS + 1) * BATCH * HID;
  unsigned short* Wv_hi   = Hall_lo + (size_t)(T_STEPS + 1) * BATCH * HID;
  unsigned short* Wv_lo   = Wv_hi + (size_t)VOCAB * HID;
  unsigned*       flags   = (unsigned*)(Wv_lo + (size_t)VOCAB * HID);

  hipMemsetAsync(flags, 0, NWG * sizeof(unsigned), stream);

  pool_fc_kernel<<<BATCH, 512, 0, stream>>>(features, fc_w, fc_b, Hall_hi, Hall_lo);
  xg_gemm_kernel<<<dim3(GATES / BN, M_ROWS / BM), 256, 0, stream>>>(
      reports, emb, W_ih, b_ih, b_hh, xg);
  {
    int n4 = VOCAB * HID / 4;
    split_kernel<<<(n4 + 255) / 256, 256, 0, stream>>>(Wv, Wv_hi, Wv_lo, n4);
  }
  {
    void* kargs[] = {(void*)&W_hh, (void*)&xg, (void*)&Hall_hi, (void*)&Hall_lo,
                     (void*)&flags};
    hipLaunchCooperativeKernel((const void*)lstm_persist_kernel, dim3(NWG),
                               dim3(256), kargs, 0, stream);
  }
  out_mfma_kernel<<<dim3(M_ROWS / 128, VOCAB / 128), 256, 0, stream>>>(
      Hall_hi + (size_t)BATCH * HID, Hall_lo + (size_t)BATCH * HID,
      Wv_hi, Wv_lo, bv, out);
}